// Round 3
// baseline (156.735 us; speedup 1.0000x reference)
//
#include <hip/hip_runtime.h>

// GaussianRegLoss: mean over [bs, nj, h, w, d] of
//   (exp(-||grid - kpt||^2)/(2*sigma^2) - sigmoid(heatmap))^2
// bs=4, nj=23, h=w=d=64, sigma=5 -> 1/(2*25) = 0.02
// Inputs: 0=kpts_gt (UNUSED), 1=kpts_pred [bs,3,nj], 2=heatmaps [bs,nj,h,w,d],
//         3=grids [bs,h*w*d,3]. Output: 1 float.

#define HWD   262144          // 64*64*64
#define NJ    23
#define BS    4
#define NTOT  24117248.0      // BS*NJ*HWD
#define BLK   256
#define VPT   4               // voxels per thread
#define BLOCKS_PER_B 256      // HWD / (BLK*VPT)
#define NBLOCKS (BS * BLOCKS_PER_B)   // 1024

__global__ __launch_bounds__(BLK) void gauss_loss_main(
    const float* __restrict__ kpts_pred,   // [BS,3,NJ]
    const float* __restrict__ heatmaps,    // [BS,NJ,HWD]
    const float* __restrict__ grids,       // [BS,HWD,3]
    float* __restrict__ partials)          // [NBLOCKS]
{
    // b derived from blockIdx only -> provably wave-uniform -> kpts become
    // scalar (SGPR) loads, no LDS staging / __syncthreads needed.
    const int b  = blockIdx.x >> 8;                       // 256 blocks per batch
    const int x4 = ((blockIdx.x & 255) * BLK + threadIdx.x) * VPT;

    // grids for 4 voxels: 12 contiguous floats (48B, 16B-aligned)
    const float* gp = grids + ((size_t)b * HWD + x4) * 3;
    const float4 g0 = *reinterpret_cast<const float4*>(gp);
    const float4 g1 = *reinterpret_cast<const float4*>(gp + 4);
    const float4 g2 = *reinterpret_cast<const float4*>(gp + 8);
    const float gx[VPT] = {g0.x, g0.w, g1.z, g2.y};
    const float gy[VPT] = {g0.y, g1.x, g1.w, g2.z};
    const float gz[VPT] = {g0.z, g1.y, g2.x, g2.w};

    const float* kp     = kpts_pred + b * 3 * NJ;         // uniform base
    const float* hmbase = heatmaps + (size_t)b * NJ * HWD + x4;

    const float LOG2E = 1.4426950408889634f;
    float acc = 0.f;

    // Double-buffered register pipeline over joints: chunks 6/6/6/5.
    // 12 loads in flight before first compute; next chunk issues while
    // current chunk computes (WAR on regs lets loads launch right after
    // the consuming VALU issues).
    float4 ha[6], hb[6];

#define LD(buf, base, n)                                                     \
    _Pragma("unroll")                                                        \
    for (int q = 0; q < (n); ++q)                                            \
        buf[q] = *reinterpret_cast<const float4*>(hmbase + (size_t)((base) + q) * HWD);

#define CP(buf, base, n)                                                     \
    _Pragma("unroll")                                                        \
    for (int q = 0; q < (n); ++q) {                                          \
        const int j = (base) + q;                                            \
        const float cx = kp[j], cy = kp[NJ + j], cz = kp[2 * NJ + j];        \
        const float hv[4] = {buf[q].x, buf[q].y, buf[q].z, buf[q].w};        \
        _Pragma("unroll")                                                    \
        for (int i = 0; i < VPT; ++i) {                                      \
            const float dx = gx[i] - cx, dy = gy[i] - cy, dz = gz[i] - cz;   \
            const float sq = dx * dx + dy * dy + dz * dz;                    \
            const float gauss = __builtin_amdgcn_exp2f(-sq * LOG2E) * 0.02f; \
            const float e     = __builtin_amdgcn_exp2f(-hv[i] * LOG2E);      \
            const float sig   = __builtin_amdgcn_rcpf(1.0f + e);             \
            const float dd    = gauss - sig;                                 \
            acc += dd * dd;                                                  \
        }                                                                    \
    }

    LD(ha, 0, 6); LD(hb, 6, 6);
    CP(ha, 0, 6); LD(ha, 12, 6);
    CP(hb, 6, 6); LD(hb, 18, 5);
    CP(ha, 12, 6);
    CP(hb, 18, 5);
#undef LD
#undef CP

    // wave (64) reduce, then cross-wave via LDS
    #pragma unroll
    for (int off = 32; off > 0; off >>= 1)
        acc += __shfl_down(acc, off, 64);
    __shared__ float s_w[BLK / 64];
    const int lane = threadIdx.x & 63, wid = threadIdx.x >> 6;
    if (lane == 0) s_w[wid] = acc;
    __syncthreads();
    if (threadIdx.x == 0)
        partials[blockIdx.x] = (s_w[0] + s_w[1]) + (s_w[2] + s_w[3]);
}

__global__ __launch_bounds__(BLK) void gauss_loss_reduce(
    const float* __restrict__ partials, float* __restrict__ out)
{
    // 1024 partials: 256 threads x float4
    const float4 v = reinterpret_cast<const float4*>(partials)[threadIdx.x];
    double acc = ((double)v.x + (double)v.y) + ((double)v.z + (double)v.w);
    #pragma unroll
    for (int off = 32; off > 0; off >>= 1)
        acc += __shfl_down(acc, off, 64);
    __shared__ double s_w[BLK / 64];
    const int lane = threadIdx.x & 63, wid = threadIdx.x >> 6;
    if (lane == 0) s_w[wid] = acc;
    __syncthreads();
    if (threadIdx.x == 0)
        out[0] = (float)(((s_w[0] + s_w[1]) + (s_w[2] + s_w[3])) / NTOT);
}

extern "C" void kernel_launch(void* const* d_in, const int* in_sizes, int n_in,
                              void* d_out, int out_size, void* d_ws, size_t ws_size,
                              hipStream_t stream) {
    // input order: 0=kpts_gt (unused), 1=kpts_pred, 2=heatmaps, 3=grids
    const float* kpts_pred = (const float*)d_in[1];
    const float* heatmaps  = (const float*)d_in[2];
    const float* grids     = (const float*)d_in[3];
    float* out      = (float*)d_out;
    float* partials = (float*)d_ws;   // NBLOCKS floats, fully overwritten each call

    gauss_loss_main<<<NBLOCKS, BLK, 0, stream>>>(kpts_pred, heatmaps, grids, partials);
    gauss_loss_reduce<<<1, BLK, 0, stream>>>(partials, out);
}

// Round 7
// 147.602 us; speedup vs baseline: 1.0619x; 1.0619x over previous
//
#include <hip/hip_runtime.h>

// GaussianRegLoss: mean over [bs, nj, h, w, d] of
//   (exp(-||grid - kpt||^2)/(2*sigma^2) - sigmoid(heatmap))^2
// bs=4, nj=23, h=w=d=64, sigma=5 -> 1/(2*25) = 0.02
// Inputs: 0=kpts_gt (UNUSED), 1=kpts_pred [bs,3,nj], 2=heatmaps [bs,nj,h,w,d],
//         3=grids [bs,h*w*d,3]. Output: 1 float.
//
// R6 == R4/R5 (resubmit; GPU acquisition timed out twice): occupancy push.
// VPT=2, 2048 blocks, launch_bounds(256,8) -> 8 waves/SIMD = 100% occupancy;
// nontemporal streaming loads via clang ext_vector_type (HIP float2/float4
// are classes and get rejected by __builtin_nontemporal_load).

#define HWD   262144          // 64*64*64
#define NJ    23
#define BS    4
#define NTOT  24117248.0      // BS*NJ*HWD
#define BLK   256
#define VPT   2               // voxels per thread
#define BLOCKS_PER_B 512      // HWD / (BLK*VPT)
#define NBLOCKS (BS * BLOCKS_PER_B)   // 2048

typedef float f32x2 __attribute__((ext_vector_type(2)));
typedef float f32x4 __attribute__((ext_vector_type(4)));

__global__ __launch_bounds__(BLK, 8) void gauss_loss_main(
    const float* __restrict__ kpts_pred,   // [BS,3,NJ]
    const float* __restrict__ heatmaps,    // [BS,NJ,HWD]
    const float* __restrict__ grids,       // [BS,HWD,3]
    float* __restrict__ partials)          // [NBLOCKS]
{
    // b from blockIdx only -> wave-uniform -> kpts via scalar (SGPR) loads.
    const int b  = blockIdx.x >> 9;                       // 512 blocks per batch
    const int x2 = ((blockIdx.x & 511) * BLK + threadIdx.x) * VPT;

    // grids for 2 voxels: 6 contiguous floats (24B, 8B-aligned)
    const float* gp = grids + ((size_t)b * HWD + x2) * 3;
    const f32x2 ga = __builtin_nontemporal_load(reinterpret_cast<const f32x2*>(gp));
    const f32x2 gb = __builtin_nontemporal_load(reinterpret_cast<const f32x2*>(gp + 2));
    const f32x2 gc = __builtin_nontemporal_load(reinterpret_cast<const f32x2*>(gp + 4));
    const float gx[VPT] = {ga.x, gb.y};
    const float gy[VPT] = {ga.y, gc.x};
    const float gz[VPT] = {gb.x, gc.y};

    const float* kp     = kpts_pred + b * 3 * NJ;         // uniform base
    const float* hmbase = heatmaps + (size_t)b * NJ * HWD + x2;

    const float LOG2E = 1.4426950408889634f;
    float acc = 0.f;

    // Register double-buffer over joints, chunks 6/6/6/5 (12 f32x2 = 24 VGPR).
    f32x2 ha[6], hb[6];

#define LD(buf, base, n)                                                     \
    _Pragma("unroll")                                                        \
    for (int q = 0; q < (n); ++q)                                            \
        buf[q] = __builtin_nontemporal_load(                                 \
            reinterpret_cast<const f32x2*>(hmbase + (size_t)((base) + q) * HWD));

#define CP(buf, base, n)                                                     \
    _Pragma("unroll")                                                        \
    for (int q = 0; q < (n); ++q) {                                          \
        const int j = (base) + q;                                            \
        const float cx = kp[j], cy = kp[NJ + j], cz = kp[2 * NJ + j];        \
        const float hv[VPT] = {buf[q].x, buf[q].y};                          \
        _Pragma("unroll")                                                    \
        for (int i = 0; i < VPT; ++i) {                                      \
            const float dx = gx[i] - cx, dy = gy[i] - cy, dz = gz[i] - cz;   \
            const float sq = dx * dx + dy * dy + dz * dz;                    \
            const float gauss = __builtin_amdgcn_exp2f(-sq * LOG2E) * 0.02f; \
            const float e     = __builtin_amdgcn_exp2f(-hv[i] * LOG2E);      \
            const float sig   = __builtin_amdgcn_rcpf(1.0f + e);             \
            const float dd    = gauss - sig;                                 \
            acc += dd * dd;                                                  \
        }                                                                    \
    }

    LD(ha, 0, 6); LD(hb, 6, 6);
    CP(ha, 0, 6); LD(ha, 12, 6);
    CP(hb, 6, 6); LD(hb, 18, 5);
    CP(ha, 12, 6);
    CP(hb, 18, 5);
#undef LD
#undef CP

    // wave (64) reduce, then cross-wave via LDS
    #pragma unroll
    for (int off = 32; off > 0; off >>= 1)
        acc += __shfl_down(acc, off, 64);
    __shared__ float s_w[BLK / 64];
    const int lane = threadIdx.x & 63, wid = threadIdx.x >> 6;
    if (lane == 0) s_w[wid] = acc;
    __syncthreads();
    if (threadIdx.x == 0)
        partials[blockIdx.x] = (s_w[0] + s_w[1]) + (s_w[2] + s_w[3]);
}

__global__ __launch_bounds__(BLK) void gauss_loss_reduce(
    const float* __restrict__ partials, float* __restrict__ out)
{
    // 2048 partials: 256 threads x 2 f32x4
    const f32x4 v0 = reinterpret_cast<const f32x4*>(partials)[threadIdx.x];
    const f32x4 v1 = reinterpret_cast<const f32x4*>(partials)[threadIdx.x + BLK];
    double acc = (((double)v0.x + (double)v0.y) + ((double)v0.z + (double)v0.w))
               + (((double)v1.x + (double)v1.y) + ((double)v1.z + (double)v1.w));
    #pragma unroll
    for (int off = 32; off > 0; off >>= 1)
        acc += __shfl_down(acc, off, 64);
    __shared__ double s_w[BLK / 64];
    const int lane = threadIdx.x & 63, wid = threadIdx.x >> 6;
    if (lane == 0) s_w[wid] = acc;
    __syncthreads();
    if (threadIdx.x == 0)
        out[0] = (float)(((s_w[0] + s_w[1]) + (s_w[2] + s_w[3])) / NTOT);
}

extern "C" void kernel_launch(void* const* d_in, const int* in_sizes, int n_in,
                              void* d_out, int out_size, void* d_ws, size_t ws_size,
                              hipStream_t stream) {
    // input order: 0=kpts_gt (unused), 1=kpts_pred, 2=heatmaps, 3=grids
    const float* kpts_pred = (const float*)d_in[1];
    const float* heatmaps  = (const float*)d_in[2];
    const float* grids     = (const float*)d_in[3];
    float* out      = (float*)d_out;
    float* partials = (float*)d_ws;   // NBLOCKS floats, fully overwritten each call

    gauss_loss_main<<<NBLOCKS, BLK, 0, stream>>>(kpts_pred, heatmaps, grids, partials);
    gauss_loss_reduce<<<1, BLK, 0, stream>>>(partials, out);
}